// Round 4
// baseline (352.419 us; speedup 1.0000x reference)
//
#include <hip/hip_runtime.h>

// ---------------------------------------------------------------------------
// DisentangleMultiHeadedAttention on MI355X (gfx950), bf16 MFMA pipeline v4.
// B=4, S=1024, HID=1024, HEADS=16, DH=64.  N_TOK=4096.
// corr_a = qa (ka+kb)^T * scale ; corr_b = qb (ka+kb)^T * scale
//   => one fused ks = k_a@Wa1^T + k_b@Wb1^T (K=2048 GEMM).
// v4: XCD-locality GEMM grid (row fastest: all col-blocks sharing an A-strip
//     pin to one XCD -> A fetched ~once per job); activation f32->bf16 fused
//     into GEMM A-staging (cvt pass now weights-only).
// ---------------------------------------------------------------------------

typedef __bf16 bf16;
typedef __bf16 bf16x4 __attribute__((ext_vector_type(4)));
typedef __bf16 bf16x8 __attribute__((ext_vector_type(8)));
typedef float  f32x4  __attribute__((ext_vector_type(4)));

#define HID_C   1024
#define S_C     1024
#define B_C     4
#define H_C     16
#define DH_C    64
#define NTOK    4096

__device__ __forceinline__ void gl_lds16(const bf16* g, bf16* l) {
    __builtin_amdgcn_global_load_lds(
        (const __attribute__((address_space(1))) void*)g,
        (__attribute__((address_space(3))) void*)l, 16, 0, 0);
}

// ---------------------------------------------------------------- convert ---
struct CvtArgs {
    const float* src[4];
    bf16*        dst[4];
    int          cum[5];    // cumulative block counts (1024 elems per block)
};

__global__ __launch_bounds__(256) void cvt_all(CvtArgs a) {
    int blk = blockIdx.x;
    int seg = 0;
    while (blk >= a.cum[seg + 1]) ++seg;
    int i = ((blk - a.cum[seg]) * 256 + threadIdx.x) * 4;
    f32x4 v = *(const f32x4*)(a.src[seg] + i);
    *(bf16x4*)(a.dst[seg] + i) = __builtin_convertvector(v, bf16x4);
}

// ------------------------------------------------------------------- GEMM ---
// C[m,n] = (sum_k A[m,k]*W[n,k] (+2nd pair) + bias) * scale
// 128x128 tile, BK=64, XOR-swizzled LDS chunks (conflict-free b128 frags).
// A path: fp32 (convert during staging, ds_write_b128) or bf16 (gl_lds16).
// W path: bf16 gl_lds16 (issued first, stays in flight during A convert).
// Grid (row=32 fastest, col=8, job): id%8 = row%8 -> the 8 col-blocks that
// share one A-strip all land on one XCD -> A-strip fetched once per job.
// mode 0: bf16 out [B,H,S,DH] | mode 1: bf16 out [B,H,DH,S] | mode 2: f32 out.
struct GemmJob {
    const void* A1; const bf16* W1;
    const void* A2; const bf16* W2;
    const float* bias1; const float* bias2;
    void* out; int mode; int a_f32; float scale;
};
struct GemmBatch { GemmJob j[5]; };

__global__ __launch_bounds__(256, 3)
void gemm_bt(GemmBatch gb) {
    const GemmJob jb = gb.j[blockIdx.z];
    const int K = HID_C;
    __shared__ bf16 a_lds[128 * 64];
    __shared__ bf16 w_lds[128 * 64];

    const int tid  = threadIdx.x;
    const int wave = tid >> 6, lane = tid & 63;
    const int quad = lane >> 4, l15 = lane & 15;
    const int swz  = l15 & 7;
    const int row0 = blockIdx.x * 128;   // row fastest -> XCD pin per strip
    const int col0 = blockIdx.y * 128;
    const int wr = (wave >> 1) * 64;
    const int wc = (wave & 1) * 64;

    f32x4 acc[4][4] = {};

    const int nkb = jb.A2 ? 32 : 16;
    for (int kb = 0; kb < nkb; ++kb) {
        const void* A = (kb < 16) ? jb.A1 : jb.A2;
        const bf16* W = (kb < 16) ? jb.W1 : jb.W2;
        const int k0 = (kb & 15) * 64;
        __syncthreads();
        // W first: async lds-direct loads stay in flight during A staging
        for (int i = 0; i < 4; ++i) {
            int q = tid + i * 256;
            int r = q >> 3, c = q & 7;
            gl_lds16(W + (size_t)(col0 + r) * K + k0 + ((c ^ (r & 7)) * 8), w_lds + q * 8);
        }
        if (jb.a_f32) {
            const float* Af = (const float*)A;
            for (int i = 0; i < 4; ++i) {
                int q = tid + i * 256;
                int r = q >> 3, c = q & 7;
                const float* src = Af + (size_t)(row0 + r) * K + k0 + ((c ^ (r & 7)) * 8);
                f32x4 lo = *(const f32x4*)src;
                f32x4 hi = *(const f32x4*)(src + 4);
                bf16x4 l4 = __builtin_convertvector(lo, bf16x4);
                bf16x4 h4 = __builtin_convertvector(hi, bf16x4);
                bf16x8 v8 = __builtin_shufflevector(l4, h4, 0, 1, 2, 3, 4, 5, 6, 7);
                *(bf16x8*)(a_lds + q * 8) = v8;   // 16B/lane contiguous: conflict-free
            }
        } else {
            const bf16* Ab = (const bf16*)A;
            for (int i = 0; i < 4; ++i) {
                int q = tid + i * 256;
                int r = q >> 3, c = q & 7;
                gl_lds16(Ab + (size_t)(row0 + r) * K + k0 + ((c ^ (r & 7)) * 8), a_lds + q * 8);
            }
        }
        __syncthreads();
        for (int kk = 0; kk < 2; ++kk) {
            const int ch = ((kk * 4 + quad) ^ swz) * 8;
            bf16x8 af[4], bw[4];
            for (int mi = 0; mi < 4; ++mi)
                af[mi] = *(const bf16x8*)(a_lds + (wr + mi * 16 + l15) * 64 + ch);
            for (int ni = 0; ni < 4; ++ni)
                bw[ni] = *(const bf16x8*)(w_lds + (wc + ni * 16 + l15) * 64 + ch);
            for (int mi = 0; mi < 4; ++mi)
                for (int ni = 0; ni < 4; ++ni)
                    acc[mi][ni] = __builtin_amdgcn_mfma_f32_16x16x32_bf16(af[mi], bw[ni], acc[mi][ni], 0, 0, 0);
        }
    }

    // epilogue.  C layout per 16x16 tile: col(n) = lane&15, row(m) = quad*4+reg.
    for (int mi = 0; mi < 4; ++mi) {
        for (int ni = 0; ni < 4; ++ni) {
            int colg = col0 + wc + ni * 16 + l15;
            float bv = jb.bias1 ? jb.bias1[colg] : 0.f;
            if (jb.bias2) bv += jb.bias2[colg];
            for (int r = 0; r < 4; ++r) {
                int rowg = row0 + wr + mi * 16 + quad * 4 + r;
                float v = (acc[mi][ni][r] + bv) * jb.scale;
                if (jb.mode == 2) {
                    ((float*)jb.out)[(size_t)rowg * HID_C + colg] = v;
                } else {
                    int b = rowg >> 10, s = rowg & 1023;
                    int h = colg >> 6,  d = colg & 63;
                    size_t idx = (jb.mode == 0)
                        ? ((size_t)((b * H_C + h) * S_C + s) * DH_C + d)
                        : ((size_t)((b * H_C + h) * DH_C + d) * S_C + s);
                    ((bf16*)jb.out)[idx] = (bf16)v;
                }
            }
        }
    }
}

// -------------------------------------------------------------- attention ---
// S^T formulation: S^T = K Q^T (A=K, B=Q), O^T = V^T P^T (A=V^T, B=P^T).
// Q pre-scaled by 1/sqrt(2*DH)*log2(e) in its projection; exp2 softmax.
// Block = 128 q-rows x one (b,h) x one stream; 4 waves x 32 rows.
// Double-buffered K/V^T staging; grid (bh, q, z): id%8 = bh%8 pins all 16
// consumers of one bh's K/V to one XCD -> K/V tiles served from that L2.
__global__ __launch_bounds__(256, 2)
void attn_fused(const bf16* __restrict__ qp_a, const bf16* __restrict__ qp_b,
                const bf16* __restrict__ ksp,
                const bf16* __restrict__ vT_a, const bf16* __restrict__ vT_b,
                const int* __restrict__ mask,
                bf16* __restrict__ ho_a, bf16* __restrict__ ho_b) {
    __shared__ bf16  k_lds[2][128 * 64];   // [key][d], XOR-swizzled chunks
    __shared__ bf16  vT_lds[2][64 * 128];  // [d][key], XOR-swizzled chunks
    __shared__ float madd[1024];           // 0 or -1e9 per key
    __shared__ bf16  p_lds[4 * 32 * 40];   // per-wave [qrow][key32] pad->40

    const int tid  = threadIdx.x;
    const int wave = tid >> 6, lane = tid & 63;
    const int quad = lane >> 4, l15 = lane & 15;
    const int swz  = l15 & 7;
    const int bh = blockIdx.x;             // XCD-locality: bh fastest
    const int b  = bh >> 4, h = bh & 15;
    const int s0 = blockIdx.y * 128;
    const bf16* qp   = blockIdx.z ? qp_b : qp_a;
    const bf16* vTp  = blockIdx.z ? vT_b : vT_a;
    bf16*       hout = blockIdx.z ? ho_b : ho_a;

    // mask -> additive table
    {
        int4 mv = *(const int4*)(mask + b * S_C + tid * 4);
        f32x4 md;
        md[0] = mv.x ? 0.f : -1e9f;
        md[1] = mv.y ? 0.f : -1e9f;
        md[2] = mv.z ? 0.f : -1e9f;
        md[3] = mv.w ? 0.f : -1e9f;
        *(f32x4*)(madd + tid * 4) = md;
    }

    // Q B-fragments from global, live in registers all kernel (pre-scaled)
    bf16x8 qf[2][2];
    for (int qt = 0; qt < 2; ++qt)
        for (int kk = 0; kk < 2; ++kk)
            qf[qt][kk] = *(const bf16x8*)(qp + ((size_t)bh * S_C + s0 + wave * 32 + qt * 16 + l15) * DH_C
                                          + kk * 32 + quad * 8);

    const bf16* kbase0 = ksp + (size_t)bh * S_C * DH_C;
    const bf16* vbase0 = vTp + (size_t)bh * DH_C * S_C;
    auto stage = [&](int kt, int buf) {
        const bf16* kb = kbase0 + kt * 128 * DH_C;
        const bf16* vb = vbase0 + kt * 128;
        for (int i = 0; i < 4; ++i) {
            int q = tid + i * 256;
            int r = q >> 3, c = q & 7;
            gl_lds16(kb + r * DH_C + ((c ^ (r & 7)) * 8), &k_lds[buf][q * 8]);
            int d = q >> 4, c16 = q & 15;
            gl_lds16(vb + (size_t)d * S_C + ((c16 ^ (d & 7)) * 8), &vT_lds[buf][q * 8]);
        }
    };

    float m_i[2] = {-1e30f, -1e30f}, l_i[2] = {0.f, 0.f};
    f32x4 Oacc[2][4] = {};                 // [qt][dt]  O^T[d][qrow]
    bf16* pw = p_lds + wave * (32 * 40);

    stage(0, 0);
    for (int kt = 0; kt < 8; ++kt) {
        const int cur = kt & 1;
        __syncthreads();                   // drains stage(kt); frees buf 1-cur
        if (kt < 7) stage(kt + 1, 1 - cur);
        const bf16* kl = k_lds[cur];
        const bf16* vl = vT_lds[cur];

        // --- S^T tiles: 8 key-tiles x 2 q-tiles ---
        f32x4 sacc[8][2] = {};
        for (int kk = 0; kk < 2; ++kk) {
            const int ch = ((kk * 4 + quad) ^ swz) * 8;
            for (int ct = 0; ct < 8; ++ct) {
                bf16x8 kf = *(const bf16x8*)(kl + (ct * 16 + l15) * 64 + ch);
                sacc[ct][0] = __builtin_amdgcn_mfma_f32_16x16x32_bf16(kf, qf[0][kk], sacc[ct][0], 0, 0, 0);
                sacc[ct][1] = __builtin_amdgcn_mfma_f32_16x16x32_bf16(kf, qf[1][kk], sacc[ct][1], 0, 0, 0);
            }
        }
        // mask add (scale already folded into Q)
        for (int ct = 0; ct < 8; ++ct) {
            f32x4 md = *(const f32x4*)(madd + kt * 128 + ct * 16 + quad * 4);
            for (int qt = 0; qt < 2; ++qt)
                for (int r = 0; r < 4; ++r)
                    sacc[ct][qt][r] += md[r];
        }
        // online softmax per q-tile (log2 domain)
        float fac[2];
        for (int qt = 0; qt < 2; ++qt) {
            float tm = sacc[0][qt][0];
            for (int ct = 0; ct < 8; ++ct)
                for (int r = 0; r < 4; ++r) tm = fmaxf(tm, sacc[ct][qt][r]);
            tm = fmaxf(tm, __shfl_xor(tm, 16, 64));
            tm = fmaxf(tm, __shfl_xor(tm, 32, 64));
            float mn = fmaxf(m_i[qt], tm);
            fac[qt] = __builtin_amdgcn_exp2f(m_i[qt] - mn);
            m_i[qt] = mn;
            float ts = 0.f;
            for (int ct = 0; ct < 8; ++ct)
                for (int r = 0; r < 4; ++r) {
                    float p = __builtin_amdgcn_exp2f(sacc[ct][qt][r] - mn);
                    sacc[ct][qt][r] = p;
                    ts += p;
                }
            ts += __shfl_xor(ts, 16, 64);
            ts += __shfl_xor(ts, 32, 64);
            l_i[qt] = l_i[qt] * fac[qt] + ts;
            for (int dt = 0; dt < 4; ++dt)
                for (int r = 0; r < 4; ++r) Oacc[qt][dt][r] *= fac[qt];
        }
        // --- PV: chunk-wise P relayout (b64 writes, wave-private) + MFMA ---
        for (int c = 0; c < 4; ++c) {
            for (int qt = 0; qt < 2; ++qt)
                for (int half = 0; half < 2; ++half) {
                    bf16x4 pv = __builtin_convertvector(sacc[2 * c + half][qt], bf16x4);
                    *(bf16x4*)(pw + (qt * 16 + l15) * 40 + half * 16 + quad * 4) = pv;
                }
            bf16x8 pf0 = *(const bf16x8*)(pw + l15 * 40 + quad * 8);
            bf16x8 pf1 = *(const bf16x8*)(pw + (16 + l15) * 40 + quad * 8);
            for (int dt = 0; dt < 4; ++dt) {
                bf16x8 vf = *(const bf16x8*)(vl + (dt * 16 + l15) * 128 + ((c * 4 + quad) ^ swz) * 8);
                Oacc[0][dt] = __builtin_amdgcn_mfma_f32_16x16x32_bf16(vf, pf0, Oacc[0][dt], 0, 0, 0);
                Oacc[1][dt] = __builtin_amdgcn_mfma_f32_16x16x32_bf16(vf, pf1, Oacc[1][dt], 0, 0, 0);
            }
        }
    }

    // epilogue: O^T frag col(n)=l15=qrow, row(m)=quad*4+r=d -> pack 4 features
    for (int qt = 0; qt < 2; ++qt) {
        float inv = 1.f / l_i[qt];
        int token = s0 + wave * 32 + qt * 16 + l15;
        for (int dt = 0; dt < 4; ++dt) {
            f32x4 o;
            for (int r = 0; r < 4; ++r) o[r] = Oacc[qt][dt][r] * inv;
            bf16x4 ob = __builtin_convertvector(o, bf16x4);
            *(bf16x4*)(hout + (size_t)(b * S_C + token) * HID_C + h * DH_C + dt * 16 + quad * 4) = ob;
        }
    }
}

// ----------------------------------------------------------------- launch ---
extern "C" void kernel_launch(void* const* d_in, const int* in_sizes, int n_in,
                              void* d_out, int out_size, void* d_ws, size_t ws_size,
                              hipStream_t stream) {
    const float* q_a  = (const float*)d_in[0];
    const float* k_a  = (const float*)d_in[1];
    const float* v_a  = (const float*)d_in[2];
    const float* q_b  = (const float*)d_in[3];
    const float* k_b  = (const float*)d_in[4];
    const float* v_b  = (const float*)d_in[5];
    const int*   mask = (const int*)  d_in[6];
    const float* Wa   = (const float*)d_in[7];
    const float* ba   = (const float*)d_in[8];
    const float* Wb   = (const float*)d_in[9];
    const float* bb   = (const float*)d_in[10];
    const float* Wo_a = (const float*)d_in[11];
    const float* bo_a = (const float*)d_in[12];
    const float* Wo_b = (const float*)d_in[13];
    const float* bo_b = (const float*)d_in[14];
    float* out = (float*)d_out;

    constexpr size_t ACT = (size_t)NTOK * HID_C;       // 4,194,304
    constexpr size_t W3  = 3 * (size_t)HID_C * HID_C;  // 3,145,728
    constexpr size_t W1  = (size_t)HID_C * HID_C;      // 1,048,576
    // softmax scale * log2(e), folded into Q projections
    const float SC2 = 0.08838834764831845f * 1.4426950408889634f;

    bf16* w = (bf16*)d_ws;
    bf16* bfWa  = w;
    bf16* bfWb  = bfWa + W3;
    bf16* bfWoA = bfWb + W3;
    bf16* bfWoB = bfWoA + W1;
    bf16* qa_p  = bfWoB + W1;
    bf16* qb_p  = qa_p + ACT;
    bf16* ks_p  = qb_p + ACT;
    bf16* vTa   = ks_p + ACT;
    bf16* vTb   = vTa + ACT;
    bf16* ha    = vTb + ACT;
    bf16* hb    = ha + ACT;

    // 1) weight fp32->bf16 converts (activations are converted inside GEMM)
    CvtArgs ca;
    const float* srcs[4] = {Wa, Wb, Wo_a, Wo_b};
    bf16* dsts[4] = {bfWa, bfWb, bfWoA, bfWoB};
    int nblk[4] = {3072, 3072, 1024, 1024};
    int cum = 0;
    for (int i = 0; i < 4; ++i) { ca.src[i] = srcs[i]; ca.dst[i] = dsts[i]; ca.cum[i] = cum; cum += nblk[i]; }
    ca.cum[4] = cum;
    cvt_all<<<cum, 256, 0, stream>>>(ca);

    // 2) all 5 projections in ONE launch (z=job, ks first; fp32 A fused-cvt)
    GemmBatch g1;
    g1.j[0] = { k_a, bfWa + W1,     k_b,     bfWb + W1, ba + 1024, bb + 1024, ks_p, 0, 1, 1.f  };
    g1.j[1] = { q_a, bfWa,          nullptr, nullptr,   ba,        nullptr,   qa_p, 0, 1, SC2 };
    g1.j[2] = { q_b, bfWb,          nullptr, nullptr,   bb,        nullptr,   qb_p, 0, 1, SC2 };
    g1.j[3] = { v_a, bfWa + 2 * W1, nullptr, nullptr,   ba + 2048, nullptr,   vTa,  1, 1, 1.f  };
    g1.j[4] = { v_b, bfWb + 2 * W1, nullptr, nullptr,   bb + 2048, nullptr,   vTb,  1, 1, 1.f  };
    gemm_bt<<<dim3(NTOK / 128, HID_C / 128, 5), 256, 0, stream>>>(g1);

    // 3) fused attention, both streams, XCD-locality grid (bh fastest)
    dim3 ga(B_C * H_C, S_C / 128, 2);  // (64, 8, 2)
    attn_fused<<<ga, 256, 0, stream>>>(qa_p, qb_p, ks_p, vTa, vTb, mask, ha, hb);

    // 4) both output projections in ONE launch -> fp32 d_out
    GemmBatch g2;
    g2.j[0] = { ha, bfWoA, nullptr, nullptr, bo_a, nullptr, (void*)out, 2, 0, 1.f };
    g2.j[1] = { hb, bfWoB, nullptr, nullptr, bo_b, nullptr,
                (void*)(out + (size_t)NTOK * HID_C), 2, 0, 1.f };
    g2.j[2] = g2.j[0]; g2.j[3] = g2.j[0]; g2.j[4] = g2.j[0];  // unused
    gemm_bt<<<dim3(NTOK / 128, HID_C / 128, 2), 256, 0, stream>>>(g2);
}

// Round 5
// 345.640 us; speedup vs baseline: 1.0196x; 1.0196x over previous
//
#include <hip/hip_runtime.h>

// ---------------------------------------------------------------------------
// DisentangleMultiHeadedAttention on MI355X (gfx950), bf16 MFMA pipeline v5.
// B=4, S=1024, HID=1024, HEADS=16, DH=64.  N_TOK=4096.
// corr_a = qa (ka+kb)^T * scale ; corr_b = qb (ka+kb)^T * scale
//   => one fused ks = k_a@Wa1^T + k_b@Wb1^T (K=2048 GEMM).
// v5: r4's XCD-locality grid (row fastest -> A-strip pinned to one XCD,
//     FETCH 202->99 MB verified) + r3's fully-async gl_lds16 staging
//     (r4's fused f32 A-convert was latency-serialized: 130 us, both pipes
//     <16% busy). Activations pre-converted in the cvt pass again.
// ---------------------------------------------------------------------------

typedef __bf16 bf16;
typedef __bf16 bf16x4 __attribute__((ext_vector_type(4)));
typedef __bf16 bf16x8 __attribute__((ext_vector_type(8)));
typedef float  f32x4  __attribute__((ext_vector_type(4)));

#define HID_C   1024
#define S_C     1024
#define B_C     4
#define H_C     16
#define DH_C    64
#define NTOK    4096

__device__ __forceinline__ void gl_lds16(const bf16* g, bf16* l) {
    __builtin_amdgcn_global_load_lds(
        (const __attribute__((address_space(1))) void*)g,
        (__attribute__((address_space(3))) void*)l, 16, 0, 0);
}

// ---------------------------------------------------------------- convert ---
struct CvtArgs {
    const float* src[10];
    bf16*        dst[10];
    int          cum[11];   // cumulative block counts (1024 elems per block)
};

__global__ __launch_bounds__(256) void cvt_all(CvtArgs a) {
    int blk = blockIdx.x;
    int seg = 0;
    while (blk >= a.cum[seg + 1]) ++seg;
    int i = ((blk - a.cum[seg]) * 256 + threadIdx.x) * 4;
    f32x4 v = *(const f32x4*)(a.src[seg] + i);
    *(bf16x4*)(a.dst[seg] + i) = __builtin_convertvector(v, bf16x4);
}

// ------------------------------------------------------------------- GEMM ---
// C[m,n] = (sum_k A[m,k]*W[n,k] (+2nd pair) + bias) * scale
// 128x128 tile, BK=64, global_load_lds(16B), XOR-swizzled LDS chunks
// (conflict-free b128 frag reads).
// Grid (row=32 fastest, col=8, job): id%8 = row%8 -> the 8 col-blocks that
// share one A-strip all land on one XCD -> A-strip fetched once per job
// [verified r4: FETCH 202->99 MB].
// mode 0: bf16 out [B,H,S,DH] | mode 1: bf16 out [B,H,DH,S] | mode 2: f32 out.
struct GemmJob {
    const bf16* A1; const bf16* W1;
    const bf16* A2; const bf16* W2;
    const float* bias1; const float* bias2;
    void* out; int mode; float scale;
};
struct GemmBatch { GemmJob j[5]; };

__global__ __launch_bounds__(256, 3)
void gemm_bt(GemmBatch gb) {
    const GemmJob jb = gb.j[blockIdx.z];
    const int K = HID_C;
    __shared__ bf16 a_lds[128 * 64];
    __shared__ bf16 w_lds[128 * 64];

    const int tid  = threadIdx.x;
    const int wave = tid >> 6, lane = tid & 63;
    const int quad = lane >> 4, l15 = lane & 15;
    const int swz  = l15 & 7;
    const int row0 = blockIdx.x * 128;   // row fastest -> XCD pin per strip
    const int col0 = blockIdx.y * 128;
    const int wr = (wave >> 1) * 64;
    const int wc = (wave & 1) * 64;

    f32x4 acc[4][4] = {};

    const int nkb = jb.A2 ? 32 : 16;
    for (int kb = 0; kb < nkb; ++kb) {
        const bf16* A = (kb < 16) ? jb.A1 : jb.A2;
        const bf16* W = (kb < 16) ? jb.W1 : jb.W2;
        const int k0 = (kb & 15) * 64;
        __syncthreads();
        // fully-async staging: 8 fire-and-forget lds-direct loads, the
        // barrier's vmcnt drain is the only wait (single latency exposure)
        for (int i = 0; i < 4; ++i) {
            int q = tid + i * 256;
            int r = q >> 3, c = q & 7;
            int gch = c ^ (r & 7);
            gl_lds16(A + (size_t)(row0 + r) * K + k0 + gch * 8, a_lds + q * 8);
            gl_lds16(W + (size_t)(col0 + r) * K + k0 + gch * 8, w_lds + q * 8);
        }
        __syncthreads();
        for (int kk = 0; kk < 2; ++kk) {
            const int ch = ((kk * 4 + quad) ^ swz) * 8;
            bf16x8 af[4], bw[4];
            for (int mi = 0; mi < 4; ++mi)
                af[mi] = *(const bf16x8*)(a_lds + (wr + mi * 16 + l15) * 64 + ch);
            for (int ni = 0; ni < 4; ++ni)
                bw[ni] = *(const bf16x8*)(w_lds + (wc + ni * 16 + l15) * 64 + ch);
            for (int mi = 0; mi < 4; ++mi)
                for (int ni = 0; ni < 4; ++ni)
                    acc[mi][ni] = __builtin_amdgcn_mfma_f32_16x16x32_bf16(af[mi], bw[ni], acc[mi][ni], 0, 0, 0);
        }
    }

    // epilogue.  C layout per 16x16 tile: col(n) = lane&15, row(m) = quad*4+reg.
    for (int mi = 0; mi < 4; ++mi) {
        for (int ni = 0; ni < 4; ++ni) {
            int colg = col0 + wc + ni * 16 + l15;
            float bv = jb.bias1 ? jb.bias1[colg] : 0.f;
            if (jb.bias2) bv += jb.bias2[colg];
            for (int r = 0; r < 4; ++r) {
                int rowg = row0 + wr + mi * 16 + quad * 4 + r;
                float v = (acc[mi][ni][r] + bv) * jb.scale;
                if (jb.mode == 2) {
                    ((float*)jb.out)[(size_t)rowg * HID_C + colg] = v;
                } else {
                    int b = rowg >> 10, s = rowg & 1023;
                    int h = colg >> 6,  d = colg & 63;
                    size_t idx = (jb.mode == 0)
                        ? ((size_t)((b * H_C + h) * S_C + s) * DH_C + d)
                        : ((size_t)((b * H_C + h) * DH_C + d) * S_C + s);
                    ((bf16*)jb.out)[idx] = (bf16)v;
                }
            }
        }
    }
}

// -------------------------------------------------------------- attention ---
// S^T formulation: S^T = K Q^T (A=K, B=Q), O^T = V^T P^T (A=V^T, B=P^T).
// Q pre-scaled by 1/sqrt(2*DH)*log2(e) in its projection; exp2 softmax.
// Block = 128 q-rows x one (b,h) x one stream; 4 waves x 32 rows.
// Double-buffered K/V^T staging; grid (bh, q, z): id%8 = bh%8 pins all 16
// consumers of one bh's K/V to one XCD -> K/V tiles served from that L2.
__global__ __launch_bounds__(256, 2)
void attn_fused(const bf16* __restrict__ qp_a, const bf16* __restrict__ qp_b,
                const bf16* __restrict__ ksp,
                const bf16* __restrict__ vT_a, const bf16* __restrict__ vT_b,
                const int* __restrict__ mask,
                bf16* __restrict__ ho_a, bf16* __restrict__ ho_b) {
    __shared__ bf16  k_lds[2][128 * 64];   // [key][d], XOR-swizzled chunks
    __shared__ bf16  vT_lds[2][64 * 128];  // [d][key], XOR-swizzled chunks
    __shared__ float madd[1024];           // 0 or -1e9 per key
    __shared__ bf16  p_lds[4 * 32 * 40];   // per-wave [qrow][key32] pad->40

    const int tid  = threadIdx.x;
    const int wave = tid >> 6, lane = tid & 63;
    const int quad = lane >> 4, l15 = lane & 15;
    const int swz  = l15 & 7;
    const int bh = blockIdx.x;             // XCD-locality: bh fastest
    const int b  = bh >> 4, h = bh & 15;
    const int s0 = blockIdx.y * 128;
    const bf16* qp   = blockIdx.z ? qp_b : qp_a;
    const bf16* vTp  = blockIdx.z ? vT_b : vT_a;
    bf16*       hout = blockIdx.z ? ho_b : ho_a;

    // mask -> additive table
    {
        int4 mv = *(const int4*)(mask + b * S_C + tid * 4);
        f32x4 md;
        md[0] = mv.x ? 0.f : -1e9f;
        md[1] = mv.y ? 0.f : -1e9f;
        md[2] = mv.z ? 0.f : -1e9f;
        md[3] = mv.w ? 0.f : -1e9f;
        *(f32x4*)(madd + tid * 4) = md;
    }

    // Q B-fragments from global, live in registers all kernel (pre-scaled)
    bf16x8 qf[2][2];
    for (int qt = 0; qt < 2; ++qt)
        for (int kk = 0; kk < 2; ++kk)
            qf[qt][kk] = *(const bf16x8*)(qp + ((size_t)bh * S_C + s0 + wave * 32 + qt * 16 + l15) * DH_C
                                          + kk * 32 + quad * 8);

    const bf16* kbase0 = ksp + (size_t)bh * S_C * DH_C;
    const bf16* vbase0 = vTp + (size_t)bh * DH_C * S_C;
    auto stage = [&](int kt, int buf) {
        const bf16* kb = kbase0 + kt * 128 * DH_C;
        const bf16* vb = vbase0 + kt * 128;
        for (int i = 0; i < 4; ++i) {
            int q = tid + i * 256;
            int r = q >> 3, c = q & 7;
            gl_lds16(kb + r * DH_C + ((c ^ (r & 7)) * 8), &k_lds[buf][q * 8]);
            int d = q >> 4, c16 = q & 15;
            gl_lds16(vb + (size_t)d * S_C + ((c16 ^ (d & 7)) * 8), &vT_lds[buf][q * 8]);
        }
    };

    float m_i[2] = {-1e30f, -1e30f}, l_i[2] = {0.f, 0.f};
    f32x4 Oacc[2][4] = {};                 // [qt][dt]  O^T[d][qrow]
    bf16* pw = p_lds + wave * (32 * 40);

    stage(0, 0);
    for (int kt = 0; kt < 8; ++kt) {
        const int cur = kt & 1;
        __syncthreads();                   // drains stage(kt); frees buf 1-cur
        if (kt < 7) stage(kt + 1, 1 - cur);
        const bf16* kl = k_lds[cur];
        const bf16* vl = vT_lds[cur];

        // --- S^T tiles: 8 key-tiles x 2 q-tiles ---
        f32x4 sacc[8][2] = {};
        for (int kk = 0; kk < 2; ++kk) {
            const int ch = ((kk * 4 + quad) ^ swz) * 8;
            for (int ct = 0; ct < 8; ++ct) {
                bf16x8 kf = *(const bf16x8*)(kl + (ct * 16 + l15) * 64 + ch);
                sacc[ct][0] = __builtin_amdgcn_mfma_f32_16x16x32_bf16(kf, qf[0][kk], sacc[ct][0], 0, 0, 0);
                sacc[ct][1] = __builtin_amdgcn_mfma_f32_16x16x32_bf16(kf, qf[1][kk], sacc[ct][1], 0, 0, 0);
            }
        }
        // mask add (scale already folded into Q)
        for (int ct = 0; ct < 8; ++ct) {
            f32x4 md = *(const f32x4*)(madd + kt * 128 + ct * 16 + quad * 4);
            for (int qt = 0; qt < 2; ++qt)
                for (int r = 0; r < 4; ++r)
                    sacc[ct][qt][r] += md[r];
        }
        // online softmax per q-tile (log2 domain)
        float fac[2];
        for (int qt = 0; qt < 2; ++qt) {
            float tm = sacc[0][qt][0];
            for (int ct = 0; ct < 8; ++ct)
                for (int r = 0; r < 4; ++r) tm = fmaxf(tm, sacc[ct][qt][r]);
            tm = fmaxf(tm, __shfl_xor(tm, 16, 64));
            tm = fmaxf(tm, __shfl_xor(tm, 32, 64));
            float mn = fmaxf(m_i[qt], tm);
            fac[qt] = __builtin_amdgcn_exp2f(m_i[qt] - mn);
            m_i[qt] = mn;
            float ts = 0.f;
            for (int ct = 0; ct < 8; ++ct)
                for (int r = 0; r < 4; ++r) {
                    float p = __builtin_amdgcn_exp2f(sacc[ct][qt][r] - mn);
                    sacc[ct][qt][r] = p;
                    ts += p;
                }
            ts += __shfl_xor(ts, 16, 64);
            ts += __shfl_xor(ts, 32, 64);
            l_i[qt] = l_i[qt] * fac[qt] + ts;
            for (int dt = 0; dt < 4; ++dt)
                for (int r = 0; r < 4; ++r) Oacc[qt][dt][r] *= fac[qt];
        }
        // --- PV: chunk-wise P relayout (b64 writes, wave-private) + MFMA ---
        for (int c = 0; c < 4; ++c) {
            for (int qt = 0; qt < 2; ++qt)
                for (int half = 0; half < 2; ++half) {
                    bf16x4 pv = __builtin_convertvector(sacc[2 * c + half][qt], bf16x4);
                    *(bf16x4*)(pw + (qt * 16 + l15) * 40 + half * 16 + quad * 4) = pv;
                }
            bf16x8 pf0 = *(const bf16x8*)(pw + l15 * 40 + quad * 8);
            bf16x8 pf1 = *(const bf16x8*)(pw + (16 + l15) * 40 + quad * 8);
            for (int dt = 0; dt < 4; ++dt) {
                bf16x8 vf = *(const bf16x8*)(vl + (dt * 16 + l15) * 128 + ((c * 4 + quad) ^ swz) * 8);
                Oacc[0][dt] = __builtin_amdgcn_mfma_f32_16x16x32_bf16(vf, pf0, Oacc[0][dt], 0, 0, 0);
                Oacc[1][dt] = __builtin_amdgcn_mfma_f32_16x16x32_bf16(vf, pf1, Oacc[1][dt], 0, 0, 0);
            }
        }
    }

    // epilogue: O^T frag col(n)=l15=qrow, row(m)=quad*4+r=d -> pack 4 features
    for (int qt = 0; qt < 2; ++qt) {
        float inv = 1.f / l_i[qt];
        int token = s0 + wave * 32 + qt * 16 + l15;
        for (int dt = 0; dt < 4; ++dt) {
            f32x4 o;
            for (int r = 0; r < 4; ++r) o[r] = Oacc[qt][dt][r] * inv;
            bf16x4 ob = __builtin_convertvector(o, bf16x4);
            *(bf16x4*)(hout + (size_t)(b * S_C + token) * HID_C + h * DH_C + dt * 16 + quad * 4) = ob;
        }
    }
}

// ----------------------------------------------------------------- launch ---
extern "C" void kernel_launch(void* const* d_in, const int* in_sizes, int n_in,
                              void* d_out, int out_size, void* d_ws, size_t ws_size,
                              hipStream_t stream) {
    const float* q_a  = (const float*)d_in[0];
    const float* k_a  = (const float*)d_in[1];
    const float* v_a  = (const float*)d_in[2];
    const float* q_b  = (const float*)d_in[3];
    const float* k_b  = (const float*)d_in[4];
    const float* v_b  = (const float*)d_in[5];
    const int*   mask = (const int*)  d_in[6];
    const float* Wa   = (const float*)d_in[7];
    const float* ba   = (const float*)d_in[8];
    const float* Wb   = (const float*)d_in[9];
    const float* bb   = (const float*)d_in[10];
    const float* Wo_a = (const float*)d_in[11];
    const float* bo_a = (const float*)d_in[12];
    const float* Wo_b = (const float*)d_in[13];
    const float* bo_b = (const float*)d_in[14];
    float* out = (float*)d_out;

    constexpr size_t ACT = (size_t)NTOK * HID_C;       // 4,194,304
    constexpr size_t W3  = 3 * (size_t)HID_C * HID_C;  // 3,145,728
    constexpr size_t W1  = (size_t)HID_C * HID_C;      // 1,048,576
    // softmax scale * log2(e), folded into Q projections
    const float SC2 = 0.08838834764831845f * 1.4426950408889634f;

    bf16* w = (bf16*)d_ws;
    bf16* bfa[6];
    for (int i = 0; i < 6; ++i) bfa[i] = w + (size_t)i * ACT;
    bf16* bfWa  = w + 6 * ACT;
    bf16* bfWb  = bfWa + W3;
    bf16* bfWoA = bfWb + W3;
    bf16* bfWoB = bfWoA + W1;
    bf16* qa_p  = bfWoB + W1;
    bf16* qb_p  = qa_p + ACT;
    bf16* ks_p  = qb_p + ACT;
    bf16* vTa   = ks_p + ACT;
    bf16* vTb   = vTa + ACT;
    bf16* ha    = vTb + ACT;
    bf16* hb    = ha + ACT;

    // 1) all fp32->bf16 converts in ONE launch (activations + weights)
    CvtArgs ca;
    const float* srcs[10] = {q_a, k_a, v_a, q_b, k_b, v_b, Wa, Wb, Wo_a, Wo_b};
    bf16* dsts[10] = {bfa[0], bfa[1], bfa[2], bfa[3], bfa[4], bfa[5], bfWa, bfWb, bfWoA, bfWoB};
    int nblk[10] = {4096, 4096, 4096, 4096, 4096, 4096, 3072, 3072, 1024, 1024};
    int cum = 0;
    for (int i = 0; i < 10; ++i) { ca.src[i] = srcs[i]; ca.dst[i] = dsts[i]; ca.cum[i] = cum; cum += nblk[i]; }
    ca.cum[10] = cum;
    cvt_all<<<cum, 256, 0, stream>>>(ca);

    // 2) all 5 projections in ONE launch (z=job, ks first: 2x-K job's blocks
    //    dispatch earliest so its tail overlaps the others)
    GemmBatch g1;
    g1.j[0] = { bfa[1], bfWa + W1,     bfa[4], bfWb + W1, ba + 1024, bb + 1024, ks_p, 0, 1.f  };
    g1.j[1] = { bfa[0], bfWa,          nullptr, nullptr,  ba,        nullptr,   qa_p, 0, SC2 };
    g1.j[2] = { bfa[3], bfWb,          nullptr, nullptr,  bb,        nullptr,   qb_p, 0, SC2 };
    g1.j[3] = { bfa[2], bfWa + 2 * W1, nullptr, nullptr,  ba + 2048, nullptr,   vTa,  1, 1.f  };
    g1.j[4] = { bfa[5], bfWb + 2 * W1, nullptr, nullptr,  bb + 2048, nullptr,   vTb,  1, 1.f  };
    gemm_bt<<<dim3(NTOK / 128, HID_C / 128, 5), 256, 0, stream>>>(g1);

    // 3) fused attention, both streams, XCD-locality grid (bh fastest)
    dim3 ga(B_C * H_C, S_C / 128, 2);  // (64, 8, 2)
    attn_fused<<<ga, 256, 0, stream>>>(qa_p, qb_p, ks_p, vTa, vTb, mask, ha, hb);

    // 4) both output projections in ONE launch -> fp32 d_out
    GemmBatch g2;
    g2.j[0] = { ha, bfWoA, nullptr, nullptr, bo_a, nullptr, (void*)out, 2, 1.f };
    g2.j[1] = { hb, bfWoB, nullptr, nullptr, bo_b, nullptr,
                (void*)(out + (size_t)NTOK * HID_C), 2, 1.f };
    g2.j[2] = g2.j[0]; g2.j[3] = g2.j[0]; g2.j[4] = g2.j[0];  // unused
    gemm_bt<<<dim3(NTOK / 128, HID_C / 128, 2), 256, 0, stream>>>(g2);
}